// Round 8
// baseline (100.261 us; speedup 1.0000x reference)
//
#include <hip/hip_runtime.h>

// Sobel 3D magnitude, separable: S=[1,2,1], D=[1,0,-1]
// gx = Sz(Sy(Dx)), gy = Sz(Dy(Sx)), gz = Dz(Sy(Sx)); out = sqrt(gx^2+gy^2+gz^2+1e-6)
// x: (2,32,64,128,128) fp32.
// R8 = R7 (no LDS/barriers, y-pass-first, marching pointers) +
//  (a) 2-loads-per-plane: each thread loads its own row (mid) + its outer halo
//      row (h-1 for even ty, h+1 for odd); the inner row comes from lane^32 via
//      __shfl_xor (wave halves hold adjacent rows). u = outer+2*mid+inner is
//      order-symmetric; v = outer-inner flips sign on odd rows, which cancels
//      in gy^2 -> no selects needed.
//  (b) depth-2 prefetch, SINGLE loop body / single emit site (R6 redo):
//      p,q row-pairs in flight, roll p<-q, q<-new; load-to-use distance = 2 iters.

typedef float floatx4 __attribute__((ext_vector_type(4)));

constexpr int W   = 128;
constexpr int H   = 128;
constexpr int DZ  = 64;
constexpr int NC  = 2 * 32;
constexpr int TH  = 8;            // output rows per block
constexpr int HBLKS = H / TH;     // 16
constexpr int ZCH = 2;            // z chunks
constexpr int ZLEN = DZ / ZCH;    // 32

__global__ __launch_bounds__(256, 6)
void sobel3d_kernel(const float* __restrict__ xg, float* __restrict__ og) {
    const int tid = threadIdx.x;
    const int tx  = tid & 31;      // w segment: pixels 4*tx..4*tx+3
    const int ty  = tid >> 5;      // row 0..7 within tile; wave half = ty parity
    int b = blockIdx.x;
    const int hblk = b % HBLKS; b /= HBLKS;
    const int zc   = b % ZCH;   b /= ZCH;
    const int nc   = b;
    const int h    = hblk * TH + ty;
    const int za   = zc * ZLEN;
    const int zb   = za + ZLEN;                  // exclusive
    const int lastv = (zb < DZ) ? zb : DZ - 1;   // last loadable plane index

    const size_t HW = (size_t)H * W;
    const float* __restrict__ xp = xg + (size_t)nc * DZ * HW;
    float* __restrict__ op       = og + (size_t)nc * DZ * HW;

    // outer halo row: h-1 for even ty (low wave half), h+1 for odd ty
    const int  h_out  = h + ((ty & 1) ? 1 : -1);
    const bool ovalid = ((unsigned)h_out < (unsigned)H);  // false only at h=0 / h=127
    const size_t roff  = (size_t)h * W + 4 * tx;
    const int    wdelta = ((ty & 1) ? W : -W);            // mid -> outer offset (elems)

    // load {mid, outer} rows of the plane at pointer p (= plane base + roff)
    auto loadpair = [&](const float* p, floatx4& mid, floatx4& out) {
        mid = *(const floatx4*)p;
        out = ovalid ? *(const floatx4*)(p + wdelta) : (floatx4){0.f, 0.f, 0.f, 0.f};
    };

    // plane pass from {mid, outer}: inner row via lane^32 shuffle.
    // cc = Sx(Sy), dd = Sx(+-Dy) (sign cancels in gy^2), ee = Dx(Sy)
    auto plane_sde = [&](floatx4 mid, floatx4 out,
                         floatx4& cc, floatx4& dd, floatx4& ee) {
        floatx4 inn;
        inn.x = __shfl_xor(mid.x, 32, 64);
        inn.y = __shfl_xor(mid.y, 32, 64);
        inn.z = __shfl_xor(mid.z, 32, 64);
        inn.w = __shfl_xor(mid.w, 32, 64);
        floatx4 u = out + 2.f * mid + inn;   // Sy (order-symmetric)
        floatx4 v = out - inn;               // +-Dy (sign flip on odd ty, harmless)
        float um1 = __shfl_up(u.w, 1, 64);   if (tx == 0)  um1 = 0.f;
        float up4 = __shfl_down(u.x, 1, 64); if (tx == 31) up4 = 0.f;
        float vm1 = __shfl_up(v.w, 1, 64);   if (tx == 0)  vm1 = 0.f;
        float vp4 = __shfl_down(v.x, 1, 64); if (tx == 31) vp4 = 0.f;
        cc.x = um1 + 2.f * u.x + u.y;
        cc.y = u.x + 2.f * u.y + u.z;
        cc.z = u.y + 2.f * u.z + u.w;
        cc.w = u.z + 2.f * u.w + up4;
        ee.x = um1 - u.y;
        ee.y = u.x - u.z;
        ee.z = u.y - u.w;
        ee.w = u.z - up4;
        dd.x = vm1 + 2.f * v.x + v.y;
        dd.y = v.x + 2.f * v.y + v.z;
        dd.z = v.y + 2.f * v.z + v.w;
        dd.w = v.z + 2.f * v.w + vp4;
    };

    // rolling 2-plane intermediates: P = plane z-1, C = plane z
    floatx4 cP, dP, eP, cC, dCv, eC;
    const float* pin = xp + (size_t)za * HW + roff;   // plane za (mid row)
    {
        floatx4 m, o;
        if (za > 0) { loadpair(pin - HW, m, o); plane_sde(m, o, cP, dP, eP); }
        else        { cP = dP = eP = (floatx4){0.f, 0.f, 0.f, 0.f}; }
        loadpair(pin, m, o); plane_sde(m, o, cC, dCv, eC);
    }
    // depth-2 prefetch: p = plane za+1, q = plane za+2 (both always < DZ)
    floatx4 pM, pO, qM, qO;
    loadpair(pin + HW,     pM, pO);
    loadpair(pin + 2 * HW, qM, qO);
    pin += 3 * HW;                                    // -> plane za+3
    float* pout = op + (size_t)za * HW + roff;

#pragma unroll 2
    for (int z = za; z < zb; ++z) {
        // prefetch plane z+3 (wave-uniform validity; beyond need -> zeros)
        floatx4 nM, nO;
        if (z + 3 <= lastv) loadpair(pin, nM, nO);
        else { nM = nO = (floatx4){0.f, 0.f, 0.f, 0.f}; }
        pin += HW;

        // compute plane z+1 intermediates (rows prefetched 2 iterations ago)
        floatx4 c2, d2, e2;
        plane_sde(pM, pO, c2, d2, e2);

        // emit output plane z
        floatx4 gx = eP + 2.f * eC + e2;
        floatx4 gy = dP + 2.f * dCv + d2;   // sign-flipped on odd ty; squared below
        floatx4 gz = cP - c2;
        floatx4 o;
        o.x = __builtin_amdgcn_sqrtf(gx.x * gx.x + gy.x * gy.x + gz.x * gz.x + 1e-6f);
        o.y = __builtin_amdgcn_sqrtf(gx.y * gx.y + gy.y * gy.y + gz.y * gz.y + 1e-6f);
        o.z = __builtin_amdgcn_sqrtf(gx.z * gx.z + gy.z * gy.z + gz.z * gz.z + 1e-6f);
        o.w = __builtin_amdgcn_sqrtf(gx.w * gx.w + gy.w * gy.w + gz.w * gz.w + 1e-6f);
        __builtin_nontemporal_store(o, (floatx4*)pout);
        pout += HW;

        // roll windows (renamed by unroll 2)
        cP = cC;  cC  = c2;
        dP = dCv; dCv = d2;
        eP = eC;  eC  = e2;
        pM = qM;  pO  = qO;
        qM = nM;  qO  = nO;
    }
}

extern "C" void kernel_launch(void* const* d_in, const int* in_sizes, int n_in,
                              void* d_out, int out_size, void* d_ws, size_t ws_size,
                              hipStream_t stream) {
    const float* x = (const float*)d_in[0];
    float* out = (float*)d_out;
    dim3 grid(NC * ZCH * HBLKS);   // 2048 blocks == full 8-blocks/CU residency
    dim3 block(256);
    sobel3d_kernel<<<grid, block, 0, stream>>>(x, out);
}